// Round 8
// baseline (288.703 us; speedup 1.0000x reference)
//
#include <hip/hip_runtime.h>
#include <hip/hip_bf16.h>

// Attention B=4,H=16,S=2048,D=64. fp32 in/out, mask int32 (nonzero=masked).
// Round 8: 64-key iterations with two independent 32-key sub-streams per iter
// (softmax of sub A overlaps MFMA of sub B), cvt_pk bf16 packing, hoisted LDS
// offsets, interleaved prepass block types.
// S^T formulation on mfma_f32_32x32x16_bf16 (layouts verified m74/m101):
//   A: lane holds A[m=lane&31][k=(lane>>5)*8+j]
//   B: lane holds B[k=(lane>>5)*8+j][n=lane&31]
//   C/D: lane holds D[row=(reg&3)+8*(reg>>2)+4*(lane>>5)][col=lane&31]
// V staged in tau key order (swap bits 2<->3 per 16-group): S^T C-layout regs
// are directly the PV B-fragment (no cross-lane transform).

#define SEQ 2048
#define DIM 64
#define NBH 64
#define LOG2E 1.44269504088896340736f
#define SCL (0.125f * LOG2E)
#define NEG_SCALED -1.25e8f

typedef short bf16x8 __attribute__((ext_vector_type(8)));
typedef float f32x4 __attribute__((ext_vector_type(4)));
typedef float f32x16 __attribute__((ext_vector_type(16)));

static __device__ __forceinline__ unsigned short f2bf(float f) {
    unsigned int u = __float_as_uint(f);
    u += 0x7fffu + ((u >> 16) & 1u);   // RNE
    return (unsigned short)(u >> 16);
}

static __device__ __forceinline__ unsigned int pkbf(float a, float b) {
    __hip_bfloat162 t = __float22bfloat162_rn(make_float2(a, b));  // v_cvt_pk_bf16_f32
    union { __hip_bfloat162 h; unsigned int u; } c; c.h = t;
    return c.u;
}

// async global->LDS, 16B per lane; LDS dest = wave-uniform base + lane*16
#define GLD16(gp, lp) __builtin_amdgcn_global_load_lds( \
    (const __attribute__((address_space(1))) unsigned int*)(gp), \
    (__attribute__((address_space(3))) unsigned int*)(lp), 16, 0, 0)

// ---------------- fused prepass (types striped x%7 = 4K:2V:1mask) ----------------
__global__ __launch_bounds__(256)
void prep_all_kernel(const float* __restrict__ K, const float* __restrict__ V,
                     const int* __restrict__ M,
                     unsigned short* __restrict__ Kb, unsigned short* __restrict__ Vt,
                     unsigned int* __restrict__ Mpt) {
    const int x  = blockIdx.x;
    const int r7 = x % 7;
    const int g  = x / 7;          // 0..1023
    const int t  = threadIdx.x;
    if (r7 < 4) {
        // K: fp32 -> bf16 row-major, 8 els/thread (idx 0..4095)
        const int idx = g * 4 + r7;
        size_t i0 = ((size_t)idx * 256 + t) * 8;
        float4 a = *(const float4*)(K + i0);
        float4 b = *(const float4*)(K + i0 + 4);
        union { uint4 u; unsigned short s[8]; } w;
        w.s[0] = f2bf(a.x); w.s[1] = f2bf(a.y); w.s[2] = f2bf(a.z); w.s[3] = f2bf(a.w);
        w.s[4] = f2bf(b.x); w.s[5] = f2bf(b.y); w.s[6] = f2bf(b.z); w.s[7] = f2bf(b.w);
        *(uint4*)(Kb + i0) = w.u;
    } else if (r7 < 6) {
        // V: fp32 -> bf16 transposed Vt[bh][d][u], u = tau(key) (idx 0..2047)
        __shared__ __align__(16) unsigned short T[64 * 64];
        const int vb = g * 2 + (r7 - 4);
        const int bh = vb >> 5;
        const int k0 = (vb & 31) * 64;
        {
            const int kk = t >> 2;                 // physical key (local)
            const int c  = t & 3;
            const int u  = (kk & ~12) | ((kk & 4) << 1) | ((kk & 8) >> 1); // swap23
            const int cs = c ^ ((u >> 3) & 3);
            const float* vp = V + ((size_t)bh * SEQ + k0 + kk) * DIM + c * 16;
            union { uint4 q[2]; unsigned short s[16]; } w;
            #pragma unroll
            for (int j = 0; j < 16; ++j) w.s[j] = f2bf(vp[j]);
            *(uint4*)&T[u * 64 + cs * 16]     = w.q[0];
            *(uint4*)&T[u * 64 + cs * 16 + 8] = w.q[1];
        }
        __syncthreads();
        {
            const int kc = t & 7;
            const int dp = t >> 3;
            const int ch = (dp >> 3) ^ (kc & 3);
            const unsigned int* T32 = (const unsigned int*)T;
            union { uint4 u; unsigned short s[8]; } o0, o1;
            #pragma unroll
            for (int i = 0; i < 8; ++i) {
                unsigned int v = T32[(8 * kc + i) * 32 + ch * 8 + (dp & 7)];
                o0.s[i] = (unsigned short)v;
                o1.s[i] = (unsigned short)(v >> 16);
            }
            unsigned short* op = Vt + ((size_t)bh * DIM + 2 * dp) * SEQ + k0 + 8 * kc;
            *(uint4*)op         = o0.u;
            *(uint4*)(op + SEQ) = o1.u;
        }
    } else {
        // mask: int32 -> 1 bit/key, transposed Mpt[b][it32][q] (idx 0..1023)
        __shared__ unsigned int Wt[64][8];
        const int b  = g >> 8;
        const int q0 = ((g >> 3) & 31) * 64;
        const int k0 = (g & 7) * 256;
        const int w  = t >> 6, l = t & 63;
        #pragma unroll 4
        for (int row = 0; row < 16; ++row) {
            const int q = q0 + w * 16 + row;
            int4 v4 = *(const int4*)(M + ((size_t)b * SEQ + q) * SEQ + k0 + l * 4);
            unsigned int nib = (unsigned int)(v4.x != 0) | ((unsigned int)(v4.y != 0) << 1)
                             | ((unsigned int)(v4.z != 0) << 2) | ((unsigned int)(v4.w != 0) << 3);
            unsigned int v = nib << (4 * (l & 7));
            v |= __shfl_xor(v, 1);
            v |= __shfl_xor(v, 2);
            v |= __shfl_xor(v, 4);
            if ((l & 7) == 0) Wt[w * 16 + row][l >> 3] = v;
        }
        __syncthreads();
        {
            const int q = t & 63, g0 = t >> 6;
            #pragma unroll
            for (int gg = 0; gg < 2; ++gg) {
                const int gi = g0 + gg * 4;
                Mpt[((size_t)b * 64 + (k0 >> 5) + gi) * SEQ + q0 + q] = Wt[q][gi];
            }
        }
    }
}

// ---------------- main ----------------
__global__ __launch_bounds__(256, 4)
void attn_main_kernel(const float* __restrict__ Q,
                      const unsigned short* __restrict__ Kb,
                      const unsigned short* __restrict__ Vt,
                      const unsigned int* __restrict__ Mpt,
                      float* __restrict__ O)
{
    const int bh   = blockIdx.y;
    const int b    = bh >> 4;
    const int q0   = blockIdx.x * 128;
    const int tid  = threadIdx.x;
    const int wave = tid >> 6;
    const int lane = tid & 63;
    const int h    = lane >> 5;    // k-half for 32x32 frags
    const int q32  = lane & 31;

    // 64-key tiles, two 32-key sub-tiles each, double-buffered: 32 KB total
    __shared__ __align__(16) unsigned short Kt[2][4096];   // [sub*2048 + key*64 + ...]
    __shared__ __align__(16) unsigned short Vs[2][4096];   // [sub*2048 + d*32 + ...]

    const unsigned short* Kbh = Kb + (size_t)bh * SEQ * DIM;
    const unsigned short* Vbh = Vt + (size_t)bh * SEQ * DIM;

    // ---- Q B-frags (Q^T): lane holds Q[q=q32][d = dc*16 + h*8 + j], scale folded ----
    bf16x8 qf[4];
    {
        const float* qp = Q + ((size_t)bh * SEQ + q0 + wave * 32 + q32) * DIM + h * 8;
        #pragma unroll
        for (int dc = 0; dc < 4; ++dc) {
            float4 xx = *(const float4*)(qp + dc * 16);
            float4 yy = *(const float4*)(qp + dc * 16 + 4);
            qf[dc][0] = (short)f2bf(xx.x * SCL); qf[dc][1] = (short)f2bf(xx.y * SCL);
            qf[dc][2] = (short)f2bf(xx.z * SCL); qf[dc][3] = (short)f2bf(xx.w * SCL);
            qf[dc][4] = (short)f2bf(yy.x * SCL); qf[dc][5] = (short)f2bf(yy.y * SCL);
            qf[dc][6] = (short)f2bf(yy.z * SCL); qf[dc][7] = (short)f2bf(yy.w * SCL);
        }
    }

    // ---- DMA lane mapping (source-address XOR swizzle, round-7 pattern) ----
    const int kkey  = wave * 8 + (lane >> 3);
    const int kclog = (lane & 7) ^ (lane >> 3);
    const unsigned short* kp = Kbh + (size_t)kkey * DIM + kclog * 8;
    const int vd    = wave * 16 + (lane >> 2);
    const int vclog = (lane & 3) ^ ((lane >> 3) & 3);   // basis (d>>1)&3
    const unsigned short* vp = Vbh + (size_t)vd * SEQ + vclog * 8;

    // ---- hoisted loop-invariant LDS read offsets (shorts) ----
    int kofs[4], vofs[4];
    #pragma unroll
    for (int dc = 0; dc < 4; ++dc)
        kofs[dc] = q32 * 64 + (((dc * 2 + h) ^ (q32 & 7)) * 8);
    #pragma unroll
    for (int kk = 0; kk < 2; ++kk)
        #pragma unroll
        for (int dh = 0; dh < 2; ++dh)
            vofs[kk * 2 + dh] = (dh * 32 + q32) * 32 + (((kk * 2 + h) ^ ((q32 >> 1) & 3)) * 8);

    // transposed mask: Mpt[b][it32][q]; one dword per lane per 32-key group
    const unsigned int* mpc = Mpt + (size_t)b * 64 * SEQ + (q0 + wave * 32 + q32);

    f32x16 acc[2];
    #pragma unroll
    for (int i = 0; i < 16; ++i) { acc[0][i] = 0.f; acc[1][i] = 0.f; }
    float lsum = 0.f;

    // prologue: stage iter-0 tiles (both subs) into buf0
    {
        unsigned short* kd = &Kt[0][wave * 512];
        unsigned short* vdst = &Vs[0][wave * 512];
        GLD16(kp, kd);
        GLD16(kp + 2048, kd + 2048);       // sub1: +32 keys * 64 d
        GLD16(vp, vdst);
        GLD16(vp + 32, vdst + 2048);       // sub1: +32 keys in Vt key-dim
    }

    for (int it = 0; it < SEQ / 64; ++it) {
        __syncthreads();   // vmcnt drained -> buf (it&1) ready for all waves

        unsigned int mw0 = mpc[0];
        unsigned int mw1 = mpc[SEQ];
        mpc += 2 * SEQ;

        if (it + 1 < SEQ / 64) {
            const unsigned short* kn = kp + (size_t)(it + 1) * 64 * DIM;
            const unsigned short* vn = vp + (size_t)(it + 1) * 64;
            const int nb = (it + 1) & 1;
            unsigned short* kd = &Kt[nb][wave * 512];
            unsigned short* vdst = &Vs[nb][wave * 512];
            GLD16(kn, kd);
            GLD16(kn + 2048, kd + 2048);
            GLD16(vn, vdst);
            GLD16(vn + 32, vdst + 2048);
        }

        const unsigned short* Ktb = Kt[it & 1];
        const unsigned short* Vsb = Vs[it & 1];

        // ---- QK^T both subs first (independent MFMA streams) ----
        f32x16 sc0, sc1;
        #pragma unroll
        for (int i = 0; i < 16; ++i) { sc0[i] = 0.f; sc1[i] = 0.f; }
        #pragma unroll
        for (int dc = 0; dc < 4; ++dc) {
            bf16x8 kf0 = *(const bf16x8*)(Ktb + kofs[dc]);
            sc0 = __builtin_amdgcn_mfma_f32_32x32x16_bf16(kf0, qf[dc], sc0, 0, 0, 0);
        }
        #pragma unroll
        for (int dc = 0; dc < 4; ++dc) {
            bf16x8 kf1 = *(const bf16x8*)(Ktb + 2048 + kofs[dc]);
            sc1 = __builtin_amdgcn_mfma_f32_32x32x16_bf16(kf1, qf[dc], sc1, 0, 0, 0);
        }

        // ---- sub0 softmax (overlaps sub1 QK MFMAs in scheduler) ----
        unsigned int pk0[8];
        {
            const unsigned int mq = mw0 >> (4 * h);
            float pv[16];
            #pragma unroll
            for (int r = 0; r < 16; ++r) {
                const int s = (r & 3) + 8 * (r >> 2);
                float e = __builtin_amdgcn_exp2f(sc0[r]);
                pv[r] = ((mq >> s) & 1u) ? 0.f : e;
                lsum += pv[r];
            }
            #pragma unroll
            for (int m = 0; m < 8; ++m) pk0[m] = pkbf(pv[2 * m], pv[2 * m + 1]);
        }

        // ---- sub0 PV ----
        #pragma unroll
        for (int kk = 0; kk < 2; ++kk) {
            union { unsigned int u[4]; bf16x8 v; } fr;
            fr.u[0] = pk0[4 * kk + 0]; fr.u[1] = pk0[4 * kk + 1];
            fr.u[2] = pk0[4 * kk + 2]; fr.u[3] = pk0[4 * kk + 3];
            #pragma unroll
            for (int dh = 0; dh < 2; ++dh) {
                bf16x8 vf = *(const bf16x8*)(Vsb + vofs[kk * 2 + dh]);
                acc[dh] = __builtin_amdgcn_mfma_f32_32x32x16_bf16(vf, fr.v, acc[dh], 0, 0, 0);
            }
        }

        // ---- sub1 softmax (overlaps sub0 PV MFMAs) ----
        unsigned int pk1[8];
        {
            const unsigned int mq = mw1 >> (4 * h);
            float pv[16];
            #pragma unroll
            for (int r = 0; r < 16; ++r) {
                const int s = (r & 3) + 8 * (r >> 2);
                float e = __builtin_amdgcn_exp2f(sc1[r]);
                pv[r] = ((mq >> s) & 1u) ? 0.f : e;
                lsum += pv[r];
            }
            #pragma unroll
            for (int m = 0; m < 8; ++m) pk1[m] = pkbf(pv[2 * m], pv[2 * m + 1]);
        }

        // ---- sub1 PV ----
        #pragma unroll
        for (int kk = 0; kk < 2; ++kk) {
            union { unsigned int u[4]; bf16x8 v; } fr;
            fr.u[0] = pk1[4 * kk + 0]; fr.u[1] = pk1[4 * kk + 1];
            fr.u[2] = pk1[4 * kk + 2]; fr.u[3] = pk1[4 * kk + 3];
            #pragma unroll
            for (int dh = 0; dh < 2; ++dh) {
                bf16x8 vf = *(const bf16x8*)(Vsb + 2048 + vofs[kk * 2 + dh]);
                acc[dh] = __builtin_amdgcn_mfma_f32_32x32x16_bf16(vf, fr.v, acc[dh], 0, 0, 0);
            }
        }
    }

    // ---- epilogue: l(q) = lsum(lane) + lsum(lane^32); store O^T C-layout ----
    lsum += __shfl_xor(lsum, 32);
    const float inv = 1.f / lsum;
    float* orow = O + ((size_t)bh * SEQ + q0 + wave * 32 + q32) * DIM;
    #pragma unroll
    for (int dh = 0; dh < 2; ++dh) {
        #pragma unroll
        for (int r23 = 0; r23 < 4; ++r23) {
            float4 w;
            w.x = acc[dh][4 * r23 + 0] * inv;
            w.y = acc[dh][4 * r23 + 1] * inv;
            w.z = acc[dh][4 * r23 + 2] * inv;
            w.w = acc[dh][4 * r23 + 3] * inv;
            *(float4*)(orow + dh * 32 + r23 * 8 + h * 4) = w;
        }
    }
}

// ---------------- fallback (round-2 kernel, used if ws too small) ----------------
__global__ __launch_bounds__(256)
void attn_fallback_kernel(const float* __restrict__ Q,
                          const float* __restrict__ K,
                          const float* __restrict__ V,
                          const int* __restrict__ mask,
                          float* __restrict__ O)
{
    const int bh   = blockIdx.y;
    const int b    = bh >> 4;
    const int q0   = blockIdx.x * 64;
    const int tid  = threadIdx.x;
    const int wave = tid >> 6;
    const int lane = tid & 63;
    const int quad = lane >> 4;
    const int l16  = lane & 15;

    __shared__ __align__(16) unsigned short Klds[32][72];
    __shared__ __align__(16) unsigned short VT[64][40];
    __shared__ __align__(16) unsigned short Plds[4][16][40];

    const float* Qb = Q + (size_t)bh * SEQ * DIM;
    const float* Kbp = K + (size_t)bh * SEQ * DIM;
    const float* Vb = V + (size_t)bh * SEQ * DIM;
    const int*   Mb = mask + (size_t)b * SEQ * SEQ;

    const int qrow_frag = q0 + wave * 16 + l16;
    bf16x8 qf0, qf1;
    {
        const float* qp = Qb + (size_t)qrow_frag * DIM + quad * 8;
        #pragma unroll
        for (int i = 0; i < 8; ++i) {
            qf0[i] = (short)f2bf(qp[i]);
            qf1[i] = (short)f2bf(qp[32 + i]);
        }
    }

    f32x4 acc[4];
    #pragma unroll
    for (int dg = 0; dg < 4; ++dg) acc[dg] = (f32x4){0.f, 0.f, 0.f, 0.f};
    float mrowv[4] = {-INFINITY, -INFINITY, -INFINITY, -INFINITY};
    float lrow[4] = {0.f, 0.f, 0.f, 0.f};

    const int skey = tid >> 3;
    const int sd0  = (tid & 7) * 8;
    const int vkey = tid & 31;
    const int vd0  = (tid >> 5) * 8;
    const int qrow_m = q0 + wave * 16 + quad * 4;

    for (int kb = 0; kb < SEQ; kb += 32) {
        __syncthreads();
        {
            const float* kpp = Kbp + (size_t)(kb + skey) * DIM + sd0;
            union { uint4 u4; unsigned short s[8]; } kw;
            #pragma unroll
            for (int i = 0; i < 8; ++i) kw.s[i] = f2bf(kpp[i]);
            *(uint4*)&Klds[skey][sd0] = kw.u4;
        }
        {
            const float* vpp = Vb + (size_t)(kb + vkey) * DIM + vd0;
            #pragma unroll
            for (int i = 0; i < 8; ++i) VT[vd0 + i][vkey] = f2bf(vpp[i]);
        }
        __syncthreads();

        f32x4 scr[2];
        scr[0] = (f32x4){0.f, 0.f, 0.f, 0.f};
        scr[1] = (f32x4){0.f, 0.f, 0.f, 0.f};
        #pragma unroll
        for (int nt = 0; nt < 2; ++nt) {
            bf16x8 kf0 = *(const bf16x8*)&Klds[nt * 16 + l16][quad * 8];
            bf16x8 kf1 = *(const bf16x8*)&Klds[nt * 16 + l16][32 + quad * 8];
            scr[nt] = __builtin_amdgcn_mfma_f32_16x16x32_bf16(qf0, kf0, scr[nt], 0, 0, 0);
            scr[nt] = __builtin_amdgcn_mfma_f32_16x16x32_bf16(qf1, kf1, scr[nt], 0, 0, 0);
        }

        float x[2][4];
        #pragma unroll
        for (int nt = 0; nt < 2; ++nt)
            #pragma unroll
            for (int r = 0; r < 4; ++r) {
                int mv = Mb[(size_t)(qrow_m + r) * SEQ + kb + nt * 16 + l16];
                x[nt][r] = mv ? NEG_SCALED : scr[nt][r] * 0.125f;
            }

        float p[2][4];
        #pragma unroll
        for (int r = 0; r < 4; ++r) {
            float rm = fmaxf(x[0][r], x[1][r]);
            #pragma unroll
            for (int off = 1; off < 16; off <<= 1)
                rm = fmaxf(rm, __shfl_xor(rm, off, 16));
            float mn = fmaxf(mrowv[r], rm);
            float alpha = exp2f((mrowv[r] - mn) * LOG2E);
            mrowv[r] = mn;
            float p0 = exp2f((x[0][r] - mn) * LOG2E);
            float p1 = exp2f((x[1][r] - mn) * LOG2E);
            p[0][r] = p0; p[1][r] = p1;
            float rs = p0 + p1;
            #pragma unroll
            for (int off = 1; off < 16; off <<= 1)
                rs += __shfl_xor(rs, off, 16);
            lrow[r] = lrow[r] * alpha + rs;
            #pragma unroll
            for (int dg = 0; dg < 4; ++dg)
                acc[dg][r] *= alpha;
        }

        #pragma unroll
        for (int nt = 0; nt < 2; ++nt)
            #pragma unroll
            for (int r = 0; r < 4; ++r)
                Plds[wave][quad * 4 + r][nt * 16 + l16] = f2bf(p[nt][r]);

        bf16x8 pf = *(const bf16x8*)&Plds[wave][l16][quad * 8];

        #pragma unroll
        for (int dg = 0; dg < 4; ++dg) {
            bf16x8 vf = *(const bf16x8*)&VT[dg * 16 + l16][quad * 8];
            acc[dg] = __builtin_amdgcn_mfma_f32_16x16x32_bf16(pf, vf, acc[dg], 0, 0, 0);
        }
    }

    float* Ob = O + (size_t)bh * SEQ * DIM;
    #pragma unroll
    for (int r = 0; r < 4; ++r) {
        float inv = 1.f / lrow[r];
        #pragma unroll
        for (int dg = 0; dg < 4; ++dg)
            Ob[(size_t)(qrow_m + r) * DIM + dg * 16 + l16] = acc[dg][r] * inv;
    }
}

extern "C" void kernel_launch(void* const* d_in, const int* in_sizes, int n_in,
                              void* d_out, int out_size, void* d_ws, size_t ws_size,
                              hipStream_t stream) {
    const float* Q = (const float*)d_in[0];
    const float* K = (const float*)d_in[1];
    const float* V = (const float*)d_in[2];
    const int* mask = (const int*)d_in[3];
    float*        O = (float*)d_out;

    const size_t szK = (size_t)NBH * SEQ * DIM * 2;        // bf16 K
    const size_t szV = (size_t)NBH * SEQ * DIM * 2;        // bf16 Vt (tau key order)
    const size_t szM = (size_t)4 * SEQ * (SEQ / 32) * 4;   // packed transposed mask
    const size_t need = szK + szV + szM;

    if (ws_size >= need) {
        unsigned short* KbW = (unsigned short*)d_ws;
        unsigned short* VtW = (unsigned short*)((char*)d_ws + szK);
        unsigned int*  MptW = (unsigned int*)((char*)d_ws + szK + szV);

        prep_all_kernel<<<dim3(7168), 256, 0, stream>>>(K, V, mask, KbW, VtW, MptW);
        attn_main_kernel<<<dim3(SEQ / 128, NBH), 256, 0, stream>>>(Q, KbW, VtW, MptW, O);
    } else {
        attn_fallback_kernel<<<dim3(SEQ / 64, NBH), 256, 0, stream>>>(Q, K, V, mask, O);
    }
}

// Round 9
// 278.884 us; speedup vs baseline: 1.0352x; 1.0352x over previous
//
#include <hip/hip_runtime.h>
#include <hip/hip_bf16.h>

// Attention B=4,H=16,S=2048,D=64. fp32 in/out, mask int32 (nonzero=masked).
// Round 9: prepass deep-pipelined (8 loads in flight/thread, latency-bound fix),
// sequential block ranges (r8 striping regressed), v_cvt_pk_bf16_f32 everywhere.
// Main: persistent-zero C operand (no per-iter sc re-zeroing).
// S^T formulation on mfma_f32_32x32x16_bf16 (layouts verified m74/m101):
//   A: lane holds A[m=lane&31][k=(lane>>5)*8+j]
//   B: lane holds B[k=(lane>>5)*8+j][n=lane&31]
//   C/D: lane holds D[row=(reg&3)+8*(reg>>2)+4*(lane>>5)][col=lane&31]
// V staged in tau key order (swap bits 2<->3 per 16-group): S^T C-layout regs
// are directly the PV B-fragment (no cross-lane transform).

#define SEQ 2048
#define DIM 64
#define NBH 64
#define LOG2E 1.44269504088896340736f
#define SCL (0.125f * LOG2E)
#define NEG_SCALED -1.25e8f

typedef short bf16x8 __attribute__((ext_vector_type(8)));
typedef float f32x4 __attribute__((ext_vector_type(4)));
typedef float f32x16 __attribute__((ext_vector_type(16)));

static __device__ __forceinline__ unsigned short f2bf(float f) {
    unsigned int u = __float_as_uint(f);
    u += 0x7fffu + ((u >> 16) & 1u);   // RNE
    return (unsigned short)(u >> 16);
}

static __device__ __forceinline__ unsigned int pkbf(float a, float b) {
    __hip_bfloat162 t = __float22bfloat162_rn(make_float2(a, b));  // v_cvt_pk_bf16_f32
    union { __hip_bfloat162 h; unsigned int u; } c; c.h = t;
    return c.u;   // low 16 = a, high 16 = b
}

// async global->LDS, 16B per lane; LDS dest = wave-uniform base + lane*16
#define GLD16(gp, lp) __builtin_amdgcn_global_load_lds( \
    (const __attribute__((address_space(1))) unsigned int*)(gp), \
    (__attribute__((address_space(3))) unsigned int*)(lp), 16, 0, 0)

// ---------------- fused prepass, sequential ranges ----------------
// blocks [0,1024): K cvt (deep-pipelined); [1024,3072): V^T tau; [3072,4096): mask
__global__ __launch_bounds__(256)
void prep_all_kernel(const float* __restrict__ K, const float* __restrict__ V,
                     const int* __restrict__ M,
                     unsigned short* __restrict__ Kb, unsigned short* __restrict__ Vt,
                     unsigned int* __restrict__ Mpt) {
    const int x = blockIdx.x;
    const int t = threadIdx.x;
    if (x < 1024) {
        // K: fp32 -> bf16. Block covers 8192 floats; thread handles 4 segments
        // of 8 floats (lane-contiguous). All 8 loads issued before any convert.
        const size_t base = (size_t)x * 8192 + t * 8;
        float4 f[4][2];
        #pragma unroll
        for (int s = 0; s < 4; ++s) {
            f[s][0] = *(const float4*)(K + base + s * 2048);
            f[s][1] = *(const float4*)(K + base + s * 2048 + 4);
        }
        #pragma unroll
        for (int s = 0; s < 4; ++s) {
            uint4 w;
            w.x = pkbf(f[s][0].x, f[s][0].y);
            w.y = pkbf(f[s][0].z, f[s][0].w);
            w.z = pkbf(f[s][1].x, f[s][1].y);
            w.w = pkbf(f[s][1].z, f[s][1].w);
            *(uint4*)(Kb + base + s * 2048) = w;
        }
    } else if (x < 3072) {
        // V: fp32 -> bf16 transposed Vt[bh][d][u], u = tau(key)
        __shared__ __align__(16) unsigned short T[64 * 64];
        const int vb = x - 1024;
        const int bh = vb >> 5;
        const int k0 = (vb & 31) * 64;
        {
            const int kk = t >> 2;                 // physical key (local)
            const int c  = t & 3;
            const int u  = (kk & ~12) | ((kk & 4) << 1) | ((kk & 8) >> 1); // swap23
            const int cs = c ^ ((u >> 3) & 3);
            const float* vp = V + ((size_t)bh * SEQ + k0 + kk) * DIM + c * 16;
            float4 g[4];
            #pragma unroll
            for (int j = 0; j < 4; ++j) g[j] = *(const float4*)(vp + j * 4);
            uint4 w0, w1;
            w0.x = pkbf(g[0].x, g[0].y); w0.y = pkbf(g[0].z, g[0].w);
            w0.z = pkbf(g[1].x, g[1].y); w0.w = pkbf(g[1].z, g[1].w);
            w1.x = pkbf(g[2].x, g[2].y); w1.y = pkbf(g[2].z, g[2].w);
            w1.z = pkbf(g[3].x, g[3].y); w1.w = pkbf(g[3].z, g[3].w);
            *(uint4*)&T[u * 64 + cs * 16]     = w0;
            *(uint4*)&T[u * 64 + cs * 16 + 8] = w1;
        }
        __syncthreads();
        {
            const int kc = t & 7;
            const int dp = t >> 3;
            const int ch = (dp >> 3) ^ (kc & 3);
            const unsigned int* T32 = (const unsigned int*)T;
            union { uint4 u; unsigned short s[8]; } o0, o1;
            #pragma unroll
            for (int i = 0; i < 8; ++i) {
                unsigned int v = T32[(8 * kc + i) * 32 + ch * 8 + (dp & 7)];
                o0.s[i] = (unsigned short)v;
                o1.s[i] = (unsigned short)(v >> 16);
            }
            unsigned short* op = Vt + ((size_t)bh * DIM + 2 * dp) * SEQ + k0 + 8 * kc;
            *(uint4*)op         = o0.u;
            *(uint4*)(op + SEQ) = o1.u;
        }
    } else {
        // mask: int32 -> 1 bit/key, transposed Mpt[b][it32][q].
        // All 16 row loads hoisted (256B in flight) before the shfl-OR tree.
        __shared__ unsigned int Wt[64][8];
        const int g  = x - 3072;               // 0..1023
        const int b  = g >> 8;
        const int q0 = ((g >> 3) & 31) * 64;
        const int k0 = (g & 7) * 256;
        const int w  = t >> 6, l = t & 63;
        int4 vals[16];
        #pragma unroll
        for (int row = 0; row < 16; ++row) {
            const int q = q0 + w * 16 + row;
            vals[row] = *(const int4*)(M + ((size_t)b * SEQ + q) * SEQ + k0 + l * 4);
        }
        #pragma unroll
        for (int row = 0; row < 16; ++row) {
            int4 v4 = vals[row];
            unsigned int nib = (unsigned int)(v4.x != 0) | ((unsigned int)(v4.y != 0) << 1)
                             | ((unsigned int)(v4.z != 0) << 2) | ((unsigned int)(v4.w != 0) << 3);
            unsigned int v = nib << (4 * (l & 7));
            v |= __shfl_xor(v, 1);
            v |= __shfl_xor(v, 2);
            v |= __shfl_xor(v, 4);
            if ((l & 7) == 0) Wt[w * 16 + row][l >> 3] = v;
        }
        __syncthreads();
        {
            const int q = t & 63, g0 = t >> 6;
            #pragma unroll
            for (int gg = 0; gg < 2; ++gg) {
                const int gi = g0 + gg * 4;
                Mpt[((size_t)b * 64 + (k0 >> 5) + gi) * SEQ + q0 + q] = Wt[q][gi];
            }
        }
    }
}

// ---------------- main ----------------
__global__ __launch_bounds__(256, 4)
void attn_main_kernel(const float* __restrict__ Q,
                      const unsigned short* __restrict__ Kb,
                      const unsigned short* __restrict__ Vt,
                      const unsigned int* __restrict__ Mpt,
                      float* __restrict__ O)
{
    const int bh   = blockIdx.y;
    const int b    = bh >> 4;
    const int q0   = blockIdx.x * 128;
    const int tid  = threadIdx.x;
    const int wave = tid >> 6;
    const int lane = tid & 63;
    const int h    = lane >> 5;    // k-half for 32x32 frags
    const int q32  = lane & 31;

    // 64-key tiles, two 32-key sub-tiles each, double-buffered: 32 KB total
    __shared__ __align__(16) unsigned short Kt[2][4096];   // [sub*2048 + key*64 + ...]
    __shared__ __align__(16) unsigned short Vs[2][4096];   // [sub*2048 + d*32 + ...]

    const unsigned short* Kbh = Kb + (size_t)bh * SEQ * DIM;
    const unsigned short* Vbh = Vt + (size_t)bh * SEQ * DIM;

    // ---- Q B-frags (Q^T): lane holds Q[q=q32][d = dc*16 + h*8 + j], scale folded ----
    bf16x8 qf[4];
    {
        const float* qp = Q + ((size_t)bh * SEQ + q0 + wave * 32 + q32) * DIM + h * 8;
        #pragma unroll
        for (int dc = 0; dc < 4; ++dc) {
            float4 xx = *(const float4*)(qp + dc * 16);
            float4 yy = *(const float4*)(qp + dc * 16 + 4);
            qf[dc][0] = (short)f2bf(xx.x * SCL); qf[dc][1] = (short)f2bf(xx.y * SCL);
            qf[dc][2] = (short)f2bf(xx.z * SCL); qf[dc][3] = (short)f2bf(xx.w * SCL);
            qf[dc][4] = (short)f2bf(yy.x * SCL); qf[dc][5] = (short)f2bf(yy.y * SCL);
            qf[dc][6] = (short)f2bf(yy.z * SCL); qf[dc][7] = (short)f2bf(yy.w * SCL);
        }
    }

    // ---- DMA lane mapping (source-address XOR swizzle) ----
    const int kkey  = wave * 8 + (lane >> 3);
    const int kclog = (lane & 7) ^ (lane >> 3);
    const unsigned short* kp = Kbh + (size_t)kkey * DIM + kclog * 8;
    const int vd    = wave * 16 + (lane >> 2);
    const int vclog = (lane & 3) ^ ((lane >> 3) & 3);   // basis (d>>1)&3
    const unsigned short* vp = Vbh + (size_t)vd * SEQ + vclog * 8;

    // ---- hoisted loop-invariant LDS read offsets (shorts) ----
    int kofs[4], vofs[4];
    #pragma unroll
    for (int dc = 0; dc < 4; ++dc)
        kofs[dc] = q32 * 64 + (((dc * 2 + h) ^ (q32 & 7)) * 8);
    #pragma unroll
    for (int kk = 0; kk < 2; ++kk)
        #pragma unroll
        for (int dh = 0; dh < 2; ++dh)
            vofs[kk * 2 + dh] = (dh * 32 + q32) * 32 + (((kk * 2 + h) ^ ((q32 >> 1) & 3)) * 8);

    // transposed mask: Mpt[b][it32][q]; one dword per lane per 32-key group
    const unsigned int* mpc = Mpt + (size_t)b * 64 * SEQ + (q0 + wave * 32 + q32);

    f32x16 acc[2];
    #pragma unroll
    for (int i = 0; i < 16; ++i) { acc[0][i] = 0.f; acc[1][i] = 0.f; }
    float lsum = 0.f;

    // persistent zero C operand (never rewritten; avoids per-iter sc zero-init)
    f32x16 zc;
    #pragma unroll
    for (int i = 0; i < 16; ++i) zc[i] = 0.f;

    // prologue: stage iter-0 tiles (both subs) into buf0
    {
        unsigned short* kd = &Kt[0][wave * 512];
        unsigned short* vdst = &Vs[0][wave * 512];
        GLD16(kp, kd);
        GLD16(kp + 2048, kd + 2048);       // sub1: +32 keys * 64 d
        GLD16(vp, vdst);
        GLD16(vp + 32, vdst + 2048);       // sub1: +32 keys in Vt key-dim
    }

    for (int it = 0; it < SEQ / 64; ++it) {
        __syncthreads();   // vmcnt drained -> buf (it&1) ready for all waves

        unsigned int mw0 = mpc[0];
        unsigned int mw1 = mpc[SEQ];
        mpc += 2 * SEQ;

        if (it + 1 < SEQ / 64) {
            const unsigned short* kn = kp + (size_t)(it + 1) * 64 * DIM;
            const unsigned short* vn = vp + (size_t)(it + 1) * 64;
            const int nb = (it + 1) & 1;
            unsigned short* kd = &Kt[nb][wave * 512];
            unsigned short* vdst = &Vs[nb][wave * 512];
            GLD16(kn, kd);
            GLD16(kn + 2048, kd + 2048);
            GLD16(vn, vdst);
            GLD16(vn + 32, vdst + 2048);
        }

        const unsigned short* Ktb = Kt[it & 1];
        const unsigned short* Vsb = Vs[it & 1];

        // ---- QK^T both subs (first MFMA uses persistent zero C) ----
        f32x16 sc0, sc1;
        {
            bf16x8 kf = *(const bf16x8*)(Ktb + kofs[0]);
            sc0 = __builtin_amdgcn_mfma_f32_32x32x16_bf16(kf, qf[0], zc, 0, 0, 0);
        }
        #pragma unroll
        for (int dc = 1; dc < 4; ++dc) {
            bf16x8 kf = *(const bf16x8*)(Ktb + kofs[dc]);
            sc0 = __builtin_amdgcn_mfma_f32_32x32x16_bf16(kf, qf[dc], sc0, 0, 0, 0);
        }
        {
            bf16x8 kf = *(const bf16x8*)(Ktb + 2048 + kofs[0]);
            sc1 = __builtin_amdgcn_mfma_f32_32x32x16_bf16(kf, qf[0], zc, 0, 0, 0);
        }
        #pragma unroll
        for (int dc = 1; dc < 4; ++dc) {
            bf16x8 kf = *(const bf16x8*)(Ktb + 2048 + kofs[dc]);
            sc1 = __builtin_amdgcn_mfma_f32_32x32x16_bf16(kf, qf[dc], sc1, 0, 0, 0);
        }

        // ---- sub0 softmax (overlaps sub1 QK MFMAs) ----
        unsigned int pk0[8];
        {
            const unsigned int mq = mw0 >> (4 * h);
            float pv[16];
            #pragma unroll
            for (int r = 0; r < 16; ++r) {
                const int s = (r & 3) + 8 * (r >> 2);
                float e = __builtin_amdgcn_exp2f(sc0[r]);
                pv[r] = ((mq >> s) & 1u) ? 0.f : e;
                lsum += pv[r];
            }
            #pragma unroll
            for (int m = 0; m < 8; ++m) pk0[m] = pkbf(pv[2 * m], pv[2 * m + 1]);
        }

        // ---- sub0 PV ----
        #pragma unroll
        for (int kk = 0; kk < 2; ++kk) {
            union { unsigned int u[4]; bf16x8 v; } fr;
            fr.u[0] = pk0[4 * kk + 0]; fr.u[1] = pk0[4 * kk + 1];
            fr.u[2] = pk0[4 * kk + 2]; fr.u[3] = pk0[4 * kk + 3];
            #pragma unroll
            for (int dh = 0; dh < 2; ++dh) {
                bf16x8 vf = *(const bf16x8*)(Vsb + vofs[kk * 2 + dh]);
                acc[dh] = __builtin_amdgcn_mfma_f32_32x32x16_bf16(vf, fr.v, acc[dh], 0, 0, 0);
            }
        }

        // ---- sub1 softmax (overlaps sub0 PV MFMAs) ----
        unsigned int pk1[8];
        {
            const unsigned int mq = mw1 >> (4 * h);
            float pv[16];
            #pragma unroll
            for (int r = 0; r < 16; ++r) {
                const int s = (r & 3) + 8 * (r >> 2);
                float e = __builtin_amdgcn_exp2f(sc1[r]);
                pv[r] = ((mq >> s) & 1u) ? 0.f : e;
                lsum += pv[r];
            }
            #pragma unroll
            for (int m = 0; m < 8; ++m) pk1[m] = pkbf(pv[2 * m], pv[2 * m + 1]);
        }

        // ---- sub1 PV ----
        #pragma unroll
        for (int kk = 0; kk < 2; ++kk) {
            union { unsigned int u[4]; bf16x8 v; } fr;
            fr.u[0] = pk1[4 * kk + 0]; fr.u[1] = pk1[4 * kk + 1];
            fr.u[2] = pk1[4 * kk + 2]; fr.u[3] = pk1[4 * kk + 3];
            #pragma unroll
            for (int dh = 0; dh < 2; ++dh) {
                bf16x8 vf = *(const bf16x8*)(Vsb + 2048 + vofs[kk * 2 + dh]);
                acc[dh] = __builtin_amdgcn_mfma_f32_32x32x16_bf16(vf, fr.v, acc[dh], 0, 0, 0);
            }
        }
    }

    // ---- epilogue: l(q) = lsum(lane) + lsum(lane^32); store O^T C-layout ----
    lsum += __shfl_xor(lsum, 32);
    const float inv = 1.f / lsum;
    float* orow = O + ((size_t)bh * SEQ + q0 + wave * 32 + q32) * DIM;
    #pragma unroll
    for (int dh = 0; dh < 2; ++dh) {
        #pragma unroll
        for (int r23 = 0; r23 < 4; ++r23) {
            float4 w;
            w.x = acc[dh][4 * r23 + 0] * inv;
            w.y = acc[dh][4 * r23 + 1] * inv;
            w.z = acc[dh][4 * r23 + 2] * inv;
            w.w = acc[dh][4 * r23 + 3] * inv;
            *(float4*)(orow + dh * 32 + r23 * 8 + h * 4) = w;
        }
    }
}

// ---------------- fallback (round-2 kernel, used if ws too small) ----------------
__global__ __launch_bounds__(256)
void attn_fallback_kernel(const float* __restrict__ Q,
                          const float* __restrict__ K,
                          const float* __restrict__ V,
                          const int* __restrict__ mask,
                          float* __restrict__ O)
{
    const int bh   = blockIdx.y;
    const int b    = bh >> 4;
    const int q0   = blockIdx.x * 64;
    const int tid  = threadIdx.x;
    const int wave = tid >> 6;
    const int lane = tid & 63;
    const int quad = lane >> 4;
    const int l16  = lane & 15;

    __shared__ __align__(16) unsigned short Klds[32][72];
    __shared__ __align__(16) unsigned short VT[64][40];
    __shared__ __align__(16) unsigned short Plds[4][16][40];

    const float* Qb = Q + (size_t)bh * SEQ * DIM;
    const float* Kbp = K + (size_t)bh * SEQ * DIM;
    const float* Vb = V + (size_t)bh * SEQ * DIM;
    const int*   Mb = mask + (size_t)b * SEQ * SEQ;

    const int qrow_frag = q0 + wave * 16 + l16;
    bf16x8 qf0, qf1;
    {
        const float* qp = Qb + (size_t)qrow_frag * DIM + quad * 8;
        #pragma unroll
        for (int i = 0; i < 8; ++i) {
            qf0[i] = (short)f2bf(qp[i]);
            qf1[i] = (short)f2bf(qp[32 + i]);
        }
    }

    f32x4 acc[4];
    #pragma unroll
    for (int dg = 0; dg < 4; ++dg) acc[dg] = (f32x4){0.f, 0.f, 0.f, 0.f};
    float mrowv[4] = {-INFINITY, -INFINITY, -INFINITY, -INFINITY};
    float lrow[4] = {0.f, 0.f, 0.f, 0.f};

    const int skey = tid >> 3;
    const int sd0  = (tid & 7) * 8;
    const int vkey = tid & 31;
    const int vd0  = (tid >> 5) * 8;
    const int qrow_m = q0 + wave * 16 + quad * 4;

    for (int kb = 0; kb < SEQ; kb += 32) {
        __syncthreads();
        {
            const float* kpp = Kbp + (size_t)(kb + skey) * DIM + sd0;
            union { uint4 u4; unsigned short s[8]; } kw;
            #pragma unroll
            for (int i = 0; i < 8; ++i) kw.s[i] = f2bf(kpp[i]);
            *(uint4*)&Klds[skey][sd0] = kw.u4;
        }
        {
            const float* vpp = Vb + (size_t)(kb + vkey) * DIM + vd0;
            #pragma unroll
            for (int i = 0; i < 8; ++i) VT[vd0 + i][vkey] = f2bf(vpp[i]);
        }
        __syncthreads();

        f32x4 scr[2];
        scr[0] = (f32x4){0.f, 0.f, 0.f, 0.f};
        scr[1] = (f32x4){0.f, 0.f, 0.f, 0.f};
        #pragma unroll
        for (int nt = 0; nt < 2; ++nt) {
            bf16x8 kf0 = *(const bf16x8*)&Klds[nt * 16 + l16][quad * 8];
            bf16x8 kf1 = *(const bf16x8*)&Klds[nt * 16 + l16][32 + quad * 8];
            scr[nt] = __builtin_amdgcn_mfma_f32_16x16x32_bf16(qf0, kf0, scr[nt], 0, 0, 0);
            scr[nt] = __builtin_amdgcn_mfma_f32_16x16x32_bf16(qf1, kf1, scr[nt], 0, 0, 0);
        }

        float x[2][4];
        #pragma unroll
        for (int nt = 0; nt < 2; ++nt)
            #pragma unroll
            for (int r = 0; r < 4; ++r) {
                int mv = Mb[(size_t)(qrow_m + r) * SEQ + kb + nt * 16 + l16];
                x[nt][r] = mv ? NEG_SCALED : scr[nt][r] * 0.125f;
            }

        float p[2][4];
        #pragma unroll
        for (int r = 0; r < 4; ++r) {
            float rm = fmaxf(x[0][r], x[1][r]);
            #pragma unroll
            for (int off = 1; off < 16; off <<= 1)
                rm = fmaxf(rm, __shfl_xor(rm, off, 16));
            float mn = fmaxf(mrowv[r], rm);
            float alpha = exp2f((mrowv[r] - mn) * LOG2E);
            mrowv[r] = mn;
            float p0 = exp2f((x[0][r] - mn) * LOG2E);
            float p1 = exp2f((x[1][r] - mn) * LOG2E);
            p[0][r] = p0; p[1][r] = p1;
            float rs = p0 + p1;
            #pragma unroll
            for (int off = 1; off < 16; off <<= 1)
                rs += __shfl_xor(rs, off, 16);
            lrow[r] = lrow[r] * alpha + rs;
            #pragma unroll
            for (int dg = 0; dg < 4; ++dg)
                acc[dg][r] *= alpha;
        }

        #pragma unroll
        for (int nt = 0; nt < 2; ++nt)
            #pragma unroll
            for (int r = 0; r < 4; ++r)
                Plds[wave][quad * 4 + r][nt * 16 + l16] = f2bf(p[nt][r]);

        bf16x8 pf = *(const bf16x8*)&Plds[wave][l16][quad * 8];

        #pragma unroll
        for (int dg = 0; dg < 4; ++dg) {
            bf16x8 vf = *(const bf16x8*)&VT[dg * 16 + l16][quad * 8];
            acc[dg] = __builtin_amdgcn_mfma_f32_16x16x32_bf16(pf, vf, acc[dg], 0, 0, 0);
        }
    }

    float* Ob = O + (size_t)bh * SEQ * DIM;
    #pragma unroll
    for (int r = 0; r < 4; ++r) {
        float inv = 1.f / lrow[r];
        #pragma unroll
        for (int dg = 0; dg < 4; ++dg)
            Ob[(size_t)(qrow_m + r) * DIM + dg * 16 + l16] = acc[dg][r] * inv;
    }
}

extern "C" void kernel_launch(void* const* d_in, const int* in_sizes, int n_in,
                              void* d_out, int out_size, void* d_ws, size_t ws_size,
                              hipStream_t stream) {
    const float* Q = (const float*)d_in[0];
    const float* K = (const float*)d_in[1];
    const float* V = (const float*)d_in[2];
    const int* mask = (const int*)d_in[3];
    float*        O = (float*)d_out;

    const size_t szK = (size_t)NBH * SEQ * DIM * 2;        // bf16 K
    const size_t szV = (size_t)NBH * SEQ * DIM * 2;        // bf16 Vt (tau key order)
    const size_t szM = (size_t)4 * SEQ * (SEQ / 32) * 4;   // packed transposed mask
    const size_t need = szK + szV + szM;

    if (ws_size >= need) {
        unsigned short* KbW = (unsigned short*)d_ws;
        unsigned short* VtW = (unsigned short*)((char*)d_ws + szK);
        unsigned int*  MptW = (unsigned int*)((char*)d_ws + szK + szV);

        prep_all_kernel<<<dim3(4096), 256, 0, stream>>>(K, V, mask, KbW, VtW, MptW);
        attn_main_kernel<<<dim3(SEQ / 128, NBH), 256, 0, stream>>>(Q, KbW, VtW, MptW, O);
    } else {
        attn_fallback_kernel<<<dim3(SEQ / 64, NBH), 256, 0, stream>>>(Q, K, V, mask, O);
    }
}